// Round 3
// baseline (453.231 us; speedup 1.0000x reference)
//
#include <hip/hip_runtime.h>
#include <math.h>

// dims
#define NPIX   131072   // B*H*W = 32*64*64
#define NOPIX  32768    // B*32*32

typedef __attribute__((ext_vector_type(8))) short bf16x8;   // 8 bf16 = 4 VGPRs
typedef __attribute__((ext_vector_type(4))) short short4v;  // 8B
typedef __attribute__((ext_vector_type(4))) float floatx4;

static __device__ __forceinline__ short f2bf(float f) {
    union { float f; unsigned u; } a; a.f = f;
    unsigned r = a.u + 0x7fffu + ((a.u >> 16) & 1u);   // RNE
    return (short)(r >> 16);
}

// ---------------------------------------------------------------------------
// prep: 16 blocks; block bb computes qwk rows [bb*16, bb*16+16)
// qwk[D][g] = sum_d qn[g][d] * Wk[D][h(g)*32+d]
// ---------------------------------------------------------------------------
__global__ __launch_bounds__(256) void prep_kernel(
    const float* __restrict__ query,        // [2][256]
    const float* __restrict__ Wk,           // [256][256]
    const float* __restrict__ rpe_bias,     // [9][16]
    const float* __restrict__ attn_scale_w, // [9][16]
    float* __restrict__ qwk,                // out [256][16]
    float* __restrict__ rpe_exp,            // out [9][16]
    float* __restrict__ rpe_scale)          // out [9][16]
{
    __shared__ float qn[16 * 33];
    __shared__ float Wt[16][260];
    int tid = threadIdx.x, bb = blockIdx.x;

    for (int i = tid; i < 512; i += 256) {
        int qq  = i >> 8;
        int rem = i & 255;
        int h   = rem >> 5;
        int d   = rem & 31;
        qn[((qq << 3) + h) * 33 + d] = query[i];
    }
    for (int i = tid; i < 16 * 256; i += 256)
        Wt[i >> 8][i & 255] = Wk[bb * 16 * 256 + i];
    __syncthreads();
    if (tid < 16) {
        float s = 0.f;
        #pragma unroll
        for (int d = 0; d < 32; ++d) { float t = qn[tid * 33 + d]; s += t * t; }
        float inv = 1.0f / ((sqrtf(s) + 1e-6f) * sqrtf(32.0f));
        #pragma unroll
        for (int d = 0; d < 32; ++d) qn[tid * 33 + d] *= inv;
    }
    __syncthreads();

    int g  = tid & 15;
    int Dl = tid >> 4;
    int h2 = g & 7;
    float acc = 0.f;
    #pragma unroll
    for (int d = 0; d < 32; ++d)
        acc += qn[g * 33 + d] * Wt[Dl][h2 * 32 + d];
    qwk[(bb * 16 + Dl) * 16 + g] = acc;

    if (bb == 0 && tid < 144) {
        float r = expf(rpe_bias[tid]);
        rpe_exp[tid]   = r;
        rpe_scale[tid] = r * attn_scale_w[tid];
    }
}

// ---------------------------------------------------------------------------
// pack: all MFMA b-fragment tensors in one kernel.
//   id in [0,4096):            Bq   [8 kc][64 lane][8 j]        <- qwk
//   id in [4096,69632):        Wvh  [8 h][2 nt][8 kc][64][8]    <- Wv blockdiag
//   id in [69632,135168):      Bo   [16 nt][8 kc][64][8]        <- Wo
// ---------------------------------------------------------------------------
__global__ __launch_bounds__(256) void pack_kernel(
    const float* __restrict__ qwk, const float* __restrict__ Wv,
    const float* __restrict__ Wo,
    short* __restrict__ Bq, short* __restrict__ Wvh, short* __restrict__ Bo)
{
    int id = blockIdx.x * 256 + threadIdx.x;   // grid covers exactly 135168
    if (id < 4096) {
        int j = id & 7, lane = (id >> 3) & 63, kc = id >> 9;
        int k = kc * 32 + ((lane >> 4) << 3) + j;
        Bq[id] = f2bf(qwk[k * 16 + (lane & 15)]);
    } else if (id < 69632) {
        int id1 = id - 4096;
        int j = id1 & 7, lane = (id1 >> 3) & 63, kc = (id1 >> 9) & 7;
        int nt = (id1 >> 12) & 1, h = id1 >> 13;
        int k = kc * 32 + ((lane >> 4) << 3) + j;
        int n = h * 32 + nt * 16 + (lane & 15);
        Wvh[id1] = f2bf(Wv[k * 256 + n]);
    } else {
        int id2 = id - 69632;
        int j = id2 & 7, lane = (id2 >> 3) & 63, kc = (id2 >> 9) & 7, nt = id2 >> 12;
        int k = kc * 32 + ((lane >> 4) << 3) + j;
        int n = nt * 16 + (lane & 15);
        Bo[id2] = f2bf(Wo[k * 256 + n]);
    }
}

// ---------------------------------------------------------------------------
// cost: cost_exp[pix][16] = exp(x[pix] . qwk)   (MFMA, N=16, 64 pixels/block)
// ---------------------------------------------------------------------------
__global__ __launch_bounds__(256) void cost_kernel(
    const float* __restrict__ x,      // [131072][256]
    const short* __restrict__ Bq,     // packed [8][64][8]
    float* __restrict__ cost_exp)     // out [131072][16]
{
    __shared__ short Xs[64][272];
    int tid = threadIdx.x;
    size_t pix0 = (size_t)blockIdx.x * 64;
    const float* xb = x + pix0 * 256;

    #pragma unroll
    for (int i = 0; i < 16; ++i) {
        int idx = tid * 4 + i * 1024;
        float4 f = *(const float4*)&xb[idx];
        short4v s;
        s.x = f2bf(f.x); s.y = f2bf(f.y); s.z = f2bf(f.z); s.w = f2bf(f.w);
        *(short4v*)&Xs[idx >> 8][idx & 255] = s;
    }
    __syncthreads();

    int lane = tid & 63, w = tid >> 6;
    int m16 = lane & 15, quad = lane >> 4;

    floatx4 acc = (floatx4){0.f, 0.f, 0.f, 0.f};
    const short* bp = Bq + (size_t)lane * 8;
    #pragma unroll
    for (int kc = 0; kc < 8; ++kc) {
        bf16x8 a = *(const bf16x8*)&Xs[w * 16 + m16][kc * 32 + quad * 8];
        bf16x8 b = *(const bf16x8*)(bp + (size_t)kc * 512);
        acc = __builtin_amdgcn_mfma_f32_16x16x32_bf16(a, b, acc, 0, 0, 0);
    }
    int mbase = w * 16 + quad * 4;
    #pragma unroll
    for (int r = 0; r < 4; ++r)
        cost_exp[(pix0 + mbase + r) * 16 + m16] = expf(acc[r]);
}

// ---------------------------------------------------------------------------
// fused: per block = 16 output pixels (half an output row).
// phase1: ces + den; phase2: wcoef[w][h] = sum_q invden*rpe_scale*ces;
// phase3: z[op][h][c] = sum_w wcoef*x[pix_w][c]  (fp32, ->bf16 LDS);
// phase4: out_pre[op][h*32+d] = z[op][h] . Wv[:,h-block]  (MFMA blockdiag)
// ---------------------------------------------------------------------------
#define ZROW 264                      // padded h-row (elements)
#define ZOP  (8 * ZROW + 8)           // padded op stride = 2120 elements
__global__ __launch_bounds__(256) void fused_kernel(
    const float* __restrict__ x,          // [131072][256]
    const float* __restrict__ cost_exp,   // [131072][16]
    const float* __restrict__ rpe_exp,    // [9][16]
    const float* __restrict__ rpe_scale,  // [9][16]
    const short* __restrict__ Wvh,        // packed blockdiag Wv
    short* __restrict__ out_pre)          // [32768][256] bf16
{
    __shared__ short zs[16 * ZOP];        // 67840 B; front aliased as ces
    __shared__ float wcoefs[16][9][8];
    __shared__ float invden[16][16];
    __shared__ int   vpix[16][9];
    float* ces = (float*)zs;              // [16][9][16] fp32 = 9216 B

    int tid = threadIdx.x;
    int blk = blockIdx.x;                 // b*64 + io*2 + half
    int b   = blk >> 6;
    int io  = (blk >> 1) & 31;
    int jo0 = (blk & 1) * 16;
    int i0  = io * 2 - 1;

    if (tid < 144) {
        int op = tid / 9, w = tid - op * 9;
        int ky = w / 3, kx = w - ky * 3;
        int i = i0 + ky, j = (jo0 + op) * 2 - 1 + kx;
        vpix[op][w] = ((unsigned)i < 64u && (unsigned)j < 64u)
                        ? (((b << 6) + i) << 6) + j : -1;
    }
    __syncthreads();

    // phase 1: ces + invden
    {
        int op = tid >> 4, g = tid & 15;
        float den = 0.f;
        #pragma unroll
        for (int w = 0; w < 9; ++w) {
            int pw = vpix[op][w];
            float ce = (pw >= 0) ? cost_exp[(size_t)pw * 16 + g] : 0.f;
            ces[(op * 9 + w) * 16 + g] = ce;
            den = fmaf(rpe_exp[w * 16 + g], ce, den);
        }
        invden[op][g] = 1.0f / den;
    }
    __syncthreads();

    // phase 2: wcoefs
    for (int it = tid; it < 16 * 72; it += 256) {
        int op = it / 72, r = it - op * 72, w = r >> 3, h = r & 7;
        float c0 = ces[(op * 9 + w) * 16 + h]     * rpe_scale[w * 16 + h]     * invden[op][h];
        float c1 = ces[(op * 9 + w) * 16 + 8 + h] * rpe_scale[w * 16 + 8 + h] * invden[op][8 + h];
        wcoefs[op][w][h] = c0 + c1;
    }
    __syncthreads();                      // ces dead; zs region reusable

    // phase 3: z (fp32 accumulate, bf16 store)
    {
        int c = tid;
        for (int op = 0; op < 16; ++op) {
            float z[8] = {0.f,0.f,0.f,0.f,0.f,0.f,0.f,0.f};
            #pragma unroll
            for (int w = 0; w < 9; ++w) {
                int pw = vpix[op][w];
                if (pw >= 0) {
                    float xv = x[(size_t)pw * 256 + c];
                    float4 wc0 = *(const float4*)&wcoefs[op][w][0];
                    float4 wc1 = *(const float4*)&wcoefs[op][w][4];
                    z[0] = fmaf(wc0.x, xv, z[0]); z[1] = fmaf(wc0.y, xv, z[1]);
                    z[2] = fmaf(wc0.z, xv, z[2]); z[3] = fmaf(wc0.w, xv, z[3]);
                    z[4] = fmaf(wc1.x, xv, z[4]); z[5] = fmaf(wc1.y, xv, z[5]);
                    z[6] = fmaf(wc1.z, xv, z[6]); z[7] = fmaf(wc1.w, xv, z[7]);
                }
            }
            #pragma unroll
            for (int h = 0; h < 8; ++h)
                zs[op * ZOP + h * ZROW + c] = f2bf(z[h]);
        }
    }
    __syncthreads();

    // phase 4: blockdiag GEMM; wave wv handles h in {2wv, 2wv+1}
    int lane = tid & 63, wv = tid >> 6;
    int m16 = lane & 15, quad = lane >> 4;
    floatx4 acc[2][2];
    #pragma unroll
    for (int a = 0; a < 2; ++a)
        #pragma unroll
        for (int n = 0; n < 2; ++n) acc[a][n] = (floatx4){0.f,0.f,0.f,0.f};

    #pragma unroll
    for (int hh = 0; hh < 2; ++hh) {
        int h = wv * 2 + hh;
        const short* bp = Wvh + ((size_t)h * 1024 + lane) * 8;   // h*2*8*64
        #pragma unroll
        for (int kc = 0; kc < 8; ++kc) {
            bf16x8 a = *(const bf16x8*)&zs[m16 * ZOP + h * ZROW + kc * 32 + quad * 8];
            bf16x8 b0 = *(const bf16x8*)(bp + (size_t)kc * 512);
            bf16x8 b1 = *(const bf16x8*)(bp + (size_t)(8 + kc) * 512);
            acc[hh][0] = __builtin_amdgcn_mfma_f32_16x16x32_bf16(a, b0, acc[hh][0], 0, 0, 0);
            acc[hh][1] = __builtin_amdgcn_mfma_f32_16x16x32_bf16(a, b1, acc[hh][1], 0, 0, 0);
        }
    }

    size_t op0 = (size_t)blk * 16;
    #pragma unroll
    for (int hh = 0; hh < 2; ++hh) {
        int h = wv * 2 + hh;
        #pragma unroll
        for (int nt = 0; nt < 2; ++nt)
            #pragma unroll
            for (int r = 0; r < 4; ++r)
                out_pre[(op0 + quad * 4 + r) * 256 + h * 32 + nt * 16 + m16]
                    = f2bf(acc[hh][nt][r]);
    }
}

// ---------------------------------------------------------------------------
// out: out[32768 x 256] = out_pre(bf16) * Wo(packed bf16); M=128 tile
// ---------------------------------------------------------------------------
__global__ __launch_bounds__(256) void out_mfma_kernel(
    const short* __restrict__ Ap,     // [32768][256] bf16
    const short* __restrict__ Bo,     // packed [16][8][64][8]
    float* __restrict__ out)          // [32768][256] fp32
{
    __shared__ short As[128 * 264];   // 67.6 KB
    int tid = threadIdx.x;
    size_t row0 = (size_t)blockIdx.x * 128;
    const short* ab = Ap + row0 * 256;

    #pragma unroll
    for (int i = 0; i < 16; ++i) {
        int idx = tid * 8 + i * 2048;
        *(bf16x8*)&As[(idx >> 8) * 264 + (idx & 255)] = *(const bf16x8*)&ab[idx];
    }
    __syncthreads();

    int lane = tid & 63, wv = tid >> 6;
    int m16 = lane & 15, quad = lane >> 4;

    floatx4 acc[2][16];
    #pragma unroll
    for (int mt = 0; mt < 2; ++mt)
        #pragma unroll
        for (int nt = 0; nt < 16; ++nt) acc[mt][nt] = (floatx4){0.f,0.f,0.f,0.f};

    const short* bp = Bo + (size_t)lane * 8;
    #pragma unroll
    for (int kc = 0; kc < 8; ++kc) {
        bf16x8 a0 = *(const bf16x8*)&As[(wv * 32 + m16) * 264 + kc * 32 + quad * 8];
        bf16x8 a1 = *(const bf16x8*)&As[(wv * 32 + 16 + m16) * 264 + kc * 32 + quad * 8];
        #pragma unroll
        for (int nt = 0; nt < 16; ++nt) {
            bf16x8 b = *(const bf16x8*)(bp + (size_t)(nt * 8 + kc) * 512);
            acc[0][nt] = __builtin_amdgcn_mfma_f32_16x16x32_bf16(a0, b, acc[0][nt], 0, 0, 0);
            acc[1][nt] = __builtin_amdgcn_mfma_f32_16x16x32_bf16(a1, b, acc[1][nt], 0, 0, 0);
        }
    }

    #pragma unroll
    for (int mt = 0; mt < 2; ++mt) {
        int rbase = wv * 32 + mt * 16 + quad * 4;
        #pragma unroll
        for (int nt = 0; nt < 16; ++nt) {
            int col = nt * 16 + m16;
            #pragma unroll
            for (int r = 0; r < 4; ++r)
                out[(row0 + rbase + r) * 256 + col] = acc[mt][nt][r];
        }
    }
}

// ---------------------------------------------------------------------------
extern "C" void kernel_launch(void* const* d_in, const int* in_sizes, int n_in,
                              void* d_out, int out_size, void* d_ws, size_t ws_size,
                              hipStream_t stream)
{
    const float* x     = (const float*)d_in[0];
    const float* query = (const float*)d_in[1];
    const float* Wk    = (const float*)d_in[2];
    const float* Wv    = (const float*)d_in[3];
    const float* rpe   = (const float*)d_in[4];
    const float* asw   = (const float*)d_in[5];
    const float* Wo    = (const float*)d_in[6];
    float* out = (float*)d_out;

    float* ws        = (float*)d_ws;
    float* qwk       = ws;                        // 4096 f
    float* rpe_exp   = ws + 4096;                 // 144 f
    float* rpe_scale = ws + 4240;                 // 144 f
    short* Bq        = (short*)(ws + 4608);       // 4096 bf16  = 2048 f
    short* Wvh       = (short*)(ws + 6656);       // 65536 bf16 = 32768 f
    short* Bo        = (short*)(ws + 39424);      // 65536 bf16 = 32768 f
    float* cost_exp  = ws + 72192;                // 2,097,152 f
    short* out_pre   = (short*)(ws + 2169344);    // 8,388,608 bf16 = 4,194,304 f
    // total ws use: ~25.5 MB

    prep_kernel<<<dim3(16), dim3(256), 0, stream>>>(query, Wk, rpe, asw,
                                                    qwk, rpe_exp, rpe_scale);
    pack_kernel<<<dim3(528), dim3(256), 0, stream>>>(qwk, Wv, Wo, Bq, Wvh, Bo);
    cost_kernel<<<dim3(NPIX / 64), dim3(256), 0, stream>>>(x, Bq, cost_exp);
    fused_kernel<<<dim3(2048), dim3(256), 0, stream>>>(x, cost_exp, rpe_exp,
                                                       rpe_scale, Wvh, out_pre);
    out_mfma_kernel<<<dim3(NOPIX / 128), dim3(256), 0, stream>>>(out_pre, Bo, out);
}

// Round 4
// 286.854 us; speedup vs baseline: 1.5800x; 1.5800x over previous
//
#include <hip/hip_runtime.h>
#include <math.h>

typedef __attribute__((ext_vector_type(8))) short bf16x8;   // 8 bf16 = 4 VGPRs
typedef __attribute__((ext_vector_type(4))) float floatx4;

static __device__ __forceinline__ short f2bf(float f) {
    union { float f; unsigned u; } a; a.f = f;
    unsigned r = a.u + 0x7fffu + ((a.u >> 16) & 1u);   // RNE
    return (short)(r >> 16);
}
static __device__ __forceinline__ float bf2f(short s) {
    union { unsigned u; float f; } c; c.u = ((unsigned)(unsigned short)s) << 16;
    return c.f;
}

// ---------------------------------------------------------------------------
// prep: 16 blocks; block bb computes qwk rows [bb*16, bb*16+16)
// ---------------------------------------------------------------------------
__global__ __launch_bounds__(256) void prep_kernel(
    const float* __restrict__ query,        // [2][256]
    const float* __restrict__ Wk,           // [256][256]
    const float* __restrict__ rpe_bias,     // [9][16]
    const float* __restrict__ attn_scale_w, // [9][16]
    float* __restrict__ qwk,                // out [256][16]
    float* __restrict__ rpe_exp,            // out [9][16]
    float* __restrict__ rpe_scale)          // out [9][16]
{
    __shared__ float qn[16 * 33];
    __shared__ float Wt[16][260];
    int tid = threadIdx.x, bb = blockIdx.x;

    for (int i = tid; i < 512; i += 256) {
        int qq  = i >> 8;
        int rem = i & 255;
        int h   = rem >> 5;
        int d   = rem & 31;
        qn[((qq << 3) + h) * 33 + d] = query[i];
    }
    for (int i = tid; i < 16 * 256; i += 256)
        Wt[i >> 8][i & 255] = Wk[bb * 16 * 256 + i];
    __syncthreads();
    if (tid < 16) {
        float s = 0.f;
        #pragma unroll
        for (int d = 0; d < 32; ++d) { float t = qn[tid * 33 + d]; s += t * t; }
        float inv = 1.0f / ((sqrtf(s) + 1e-6f) * sqrtf(32.0f));
        #pragma unroll
        for (int d = 0; d < 32; ++d) qn[tid * 33 + d] *= inv;
    }
    __syncthreads();

    int g  = tid & 15;
    int Dl = tid >> 4;
    int h2 = g & 7;
    float acc = 0.f;
    #pragma unroll
    for (int d = 0; d < 32; ++d)
        acc += qn[g * 33 + d] * Wt[Dl][h2 * 32 + d];
    qwk[(bb * 16 + Dl) * 16 + g] = acc;

    if (bb == 0 && tid < 144) {
        float r = expf(rpe_bias[tid]);
        rpe_exp[tid]   = r;
        rpe_scale[tid] = r * attn_scale_w[tid];
    }
}

// ---------------------------------------------------------------------------
// pack: MFMA b-fragment tensors.
//   [0,4096):          Bq  [8 kc][64 lane][8 j]       <- qwk
//   [4096,69632):      Wvh [8 h][2 nt][8 kc][64][8]   <- Wv blockdiag
//   [69632,135168):    Bo  [16 nt][8 kc][64][8]       <- Wo
// ---------------------------------------------------------------------------
__global__ __launch_bounds__(256) void pack_kernel(
    const float* __restrict__ qwk, const float* __restrict__ Wv,
    const float* __restrict__ Wo,
    short* __restrict__ Bq, short* __restrict__ Wvh, short* __restrict__ Bo)
{
    int id = blockIdx.x * 256 + threadIdx.x;   // 135168 total
    if (id < 4096) {
        int j = id & 7, lane = (id >> 3) & 63, kc = id >> 9;
        int k = kc * 32 + ((lane >> 4) << 3) + j;
        Bq[id] = f2bf(qwk[k * 16 + (lane & 15)]);
    } else if (id < 69632) {
        int id1 = id - 4096;
        int j = id1 & 7, lane = (id1 >> 3) & 63, kc = (id1 >> 9) & 7;
        int nt = (id1 >> 12) & 1, h = id1 >> 13;
        int k = kc * 32 + ((lane >> 4) << 3) + j;
        int n = h * 32 + nt * 16 + (lane & 15);
        Wvh[id1] = f2bf(Wv[k * 256 + n]);
    } else {
        int id2 = id - 69632;
        int j = id2 & 7, lane = (id2 >> 3) & 63, kc = (id2 >> 9) & 7, nt = id2 >> 12;
        int k = kc * 32 + ((lane >> 4) << 3) + j;
        int n = nt * 16 + (lane & 15);
        Bo[id2] = f2bf(Wo[k * 256 + n]);
    }
}

// ---------------------------------------------------------------------------
// fused mega-kernel: block = 16 output pixels (half an output row), 512 thr.
// P0: stage x window (3x33 px, pad to 112 rows) -> bf16 LDS
// P1: ces[p][g] = exp(Xw . Bq)  via MFMA (7 M-tiles over 7 waves)
// P2: invden; wcoef[op][w][h] = sum_q rpe_scale*ces*invden
// P3: z[op][h][c] = sum_w wcoef * Xw   (fp32 VALU, LDS only)
// P4: pre[op][h*32+d] = z_h . Wv_h     (MFMA blockdiag, 1 head/wave)
// P5: out[op][:] = pre[op][:] . Wo     (MFMA, out_tr aliased over Xw)
// ---------------------------------------------------------------------------
#define XROW 264
#define ZROW 264
#define ZOP  2120
__global__ __launch_bounds__(512) void fused_kernel(
    const float* __restrict__ x,          // [131072][256] fp32
    const float* __restrict__ rpe_exp,    // [9][16]
    const float* __restrict__ rpe_scale,  // [9][16]
    const short* __restrict__ Bq,         // [4096]
    const short* __restrict__ Wvh,        // [65536]
    const short* __restrict__ Bo,         // [65536]
    float* __restrict__ out)              // [32768][256] fp32
{
    __shared__ short Xw[112 * XROW];      // 59136 B; aliased as out_tr in P4/P5
    __shared__ short zs[16 * ZOP];        // 67840 B
    __shared__ float ces[112 * 17];       // 7616 B
    __shared__ float wcoefs[16][9][8];    // 4608 B
    __shared__ float invden[16][16];      // 1024 B   (total 140224 B)

    int tid  = threadIdx.x;
    int lane = tid & 63, wv = tid >> 6;
    int m16  = lane & 15, quad = lane >> 4;

    int blk = blockIdx.x;                 // b*64 + io*2 + hf
    int b   = blk >> 6;
    int io  = (blk >> 1) & 31;
    int hf  = blk & 1;
    int i0  = io * 2 - 1;
    int jbase = hf * 32 - 1;

    // ---- P0: stage window, coalesced, zero-fill OOB/pad ----
    #pragma unroll
    for (int i = 0; i < 7; ++i) {
        int it  = tid + i * 512;          // 0..3583 = 112 rows x 32 chunks
        int row = it >> 5;
        int l   = it & 31;                // 8-channel chunk
        int ky  = row / 34;
        int jloc = row - ky * 34;
        int ii = i0 + ky, jj = jbase + jloc;
        bool valid = (ky < 3) && (jloc < 33) &&
                     ((unsigned)ii < 64u) && ((unsigned)jj < 64u);
        bf16x8 s;
        if (valid) {
            const float* xp = x + ((size_t)(((b << 6) + ii) << 6) + jj) * 256 + l * 8;
            float4 f0 = *(const float4*)xp;
            float4 f1 = *(const float4*)(xp + 4);
            s[0] = f2bf(f0.x); s[1] = f2bf(f0.y); s[2] = f2bf(f0.z); s[3] = f2bf(f0.w);
            s[4] = f2bf(f1.x); s[5] = f2bf(f1.y); s[6] = f2bf(f1.z); s[7] = f2bf(f1.w);
        } else {
            #pragma unroll
            for (int j = 0; j < 8; ++j) s[j] = 0;
        }
        *(bf16x8*)&Xw[row * XROW + l * 8] = s;
    }
    __syncthreads();

    // ---- P1: cost MFMA -> ces (waves 0..6, 16 rows each) ----
    if (wv < 7) {
        floatx4 acc = (floatx4){0.f, 0.f, 0.f, 0.f};
        const short* bp = Bq + lane * 8;
        #pragma unroll
        for (int kc = 0; kc < 8; ++kc) {
            bf16x8 a = *(const bf16x8*)&Xw[(wv * 16 + m16) * XROW + kc * 32 + quad * 8];
            bf16x8 bb = *(const bf16x8*)(bp + kc * 512);
            acc = __builtin_amdgcn_mfma_f32_16x16x32_bf16(a, bb, acc, 0, 0, 0);
        }
        #pragma unroll
        for (int r = 0; r < 4; ++r) {
            int p = wv * 16 + quad * 4 + r;
            int ky = p / 34, jloc = p - ky * 34;
            int ii = i0 + ky, jj = jbase + jloc;
            bool valid = (ky < 3) && (jloc < 33) &&
                         ((unsigned)ii < 64u) && ((unsigned)jj < 64u);
            ces[p * 17 + m16] = valid ? expf(acc[r]) : 0.f;
        }
    }
    __syncthreads();

    // ---- P2a: invden ----
    if (tid < 256) {
        int op = tid >> 4, g = tid & 15;
        float den = 0.f;
        #pragma unroll
        for (int w = 0; w < 9; ++w) {
            int ky = w / 3, kx = w - ky * 3;
            int row = ky * 34 + 2 * op + kx;
            den = fmaf(rpe_exp[w * 16 + g], ces[row * 17 + g], den);
        }
        invden[op][g] = 1.0f / den;
    }
    __syncthreads();

    // ---- P2b: wcoefs ----
    for (int it = tid; it < 1152; it += 512) {
        int op = it / 72, r = it - op * 72;
        int w = r >> 3, h = r & 7;
        int ky = w / 3, kx = w - ky * 3;
        int row = ky * 34 + 2 * op + kx;
        wcoefs[op][w][h] =
            ces[row * 17 + h]     * rpe_scale[w * 16 + h]     * invden[op][h] +
            ces[row * 17 + 8 + h] * rpe_scale[w * 16 + 8 + h] * invden[op][8 + h];
    }
    __syncthreads();

    // ---- P3: z combine (thread = (c, op-half)), all LDS ----
    {
        int c   = tid & 255;
        int opg = tid >> 8;               // 0 or 1
        #pragma unroll
        for (int oo = 0; oo < 8; ++oo) {
            int op = opg * 8 + oo;
            float z0=0.f,z1=0.f,z2=0.f,z3=0.f,z4=0.f,z5=0.f,z6=0.f,z7=0.f;
            #pragma unroll
            for (int w = 0; w < 9; ++w) {
                int ky = w / 3, kx = w - ky * 3;
                float xv = bf2f(Xw[(ky * 34 + 2 * op + kx) * XROW + c]);
                float4 wc0 = *(const float4*)&wcoefs[op][w][0];
                float4 wc1 = *(const float4*)&wcoefs[op][w][4];
                z0 = fmaf(wc0.x, xv, z0); z1 = fmaf(wc0.y, xv, z1);
                z2 = fmaf(wc0.z, xv, z2); z3 = fmaf(wc0.w, xv, z3);
                z4 = fmaf(wc1.x, xv, z4); z5 = fmaf(wc1.y, xv, z5);
                z6 = fmaf(wc1.z, xv, z6); z7 = fmaf(wc1.w, xv, z7);
            }
            short* zp = &zs[op * ZOP + c];
            zp[0*ZROW] = f2bf(z0); zp[1*ZROW] = f2bf(z1);
            zp[2*ZROW] = f2bf(z2); zp[3*ZROW] = f2bf(z3);
            zp[4*ZROW] = f2bf(z4); zp[5*ZROW] = f2bf(z5);
            zp[6*ZROW] = f2bf(z6); zp[7*ZROW] = f2bf(z7);
        }
    }
    __syncthreads();                      // also: Xw now dead -> reusable

    // ---- P4: blockdiag z . Wv, head = wave; write out_tr (alias Xw) ----
    {
        short* out_tr = Xw;
        int h = wv;
        floatx4 acc0 = (floatx4){0.f,0.f,0.f,0.f};
        floatx4 acc1 = (floatx4){0.f,0.f,0.f,0.f};
        const short* bp = Wvh + h * 8192 + lane * 8;
        #pragma unroll
        for (int kc = 0; kc < 8; ++kc) {
            bf16x8 a  = *(const bf16x8*)&zs[m16 * ZOP + h * ZROW + kc * 32 + quad * 8];
            bf16x8 b0 = *(const bf16x8*)(bp + kc * 512);
            bf16x8 b1 = *(const bf16x8*)(bp + 4096 + kc * 512);
            acc0 = __builtin_amdgcn_mfma_f32_16x16x32_bf16(a, b0, acc0, 0, 0, 0);
            acc1 = __builtin_amdgcn_mfma_f32_16x16x32_bf16(a, b1, acc1, 0, 0, 0);
        }
        #pragma unroll
        for (int r = 0; r < 4; ++r) {
            out_tr[(quad * 4 + r) * XROW + h * 32 + m16]      = f2bf(acc0[r]);
            out_tr[(quad * 4 + r) * XROW + h * 32 + 16 + m16] = f2bf(acc1[r]);
        }
    }
    __syncthreads();

    // ---- P5: out = out_tr . Wo (nt pair = wave), write fp32 ----
    {
        const short* out_tr = Xw;
        floatx4 acc0 = (floatx4){0.f,0.f,0.f,0.f};
        floatx4 acc1 = (floatx4){0.f,0.f,0.f,0.f};
        int nt0 = wv * 2;
        const short* bp = Bo + nt0 * 4096 + lane * 8;
        #pragma unroll
        for (int kc = 0; kc < 8; ++kc) {
            bf16x8 a  = *(const bf16x8*)&out_tr[m16 * XROW + kc * 32 + quad * 8];
            bf16x8 b0 = *(const bf16x8*)(bp + kc * 512);
            bf16x8 b1 = *(const bf16x8*)(bp + 4096 + kc * 512);
            acc0 = __builtin_amdgcn_mfma_f32_16x16x32_bf16(a, b0, acc0, 0, 0, 0);
            acc1 = __builtin_amdgcn_mfma_f32_16x16x32_bf16(a, b1, acc1, 0, 0, 0);
        }
        size_t op0 = (size_t)blk * 16;
        #pragma unroll
        for (int r = 0; r < 4; ++r) {
            out[(op0 + quad * 4 + r) * 256 + nt0 * 16 + m16]      = acc0[r];
            out[(op0 + quad * 4 + r) * 256 + (nt0 + 1) * 16 + m16] = acc1[r];
        }
    }
}

// ---------------------------------------------------------------------------
extern "C" void kernel_launch(void* const* d_in, const int* in_sizes, int n_in,
                              void* d_out, int out_size, void* d_ws, size_t ws_size,
                              hipStream_t stream)
{
    const float* x     = (const float*)d_in[0];
    const float* query = (const float*)d_in[1];
    const float* Wk    = (const float*)d_in[2];
    const float* Wv    = (const float*)d_in[3];
    const float* rpe   = (const float*)d_in[4];
    const float* asw   = (const float*)d_in[5];
    const float* Wo    = (const float*)d_in[6];
    float* out = (float*)d_out;

    float* ws        = (float*)d_ws;
    float* qwk       = ws;                        // 4096 f
    float* rpe_exp   = ws + 4096;                 // 144 f
    float* rpe_scale = ws + 4240;                 // 144 f
    short* Bq        = (short*)(ws + 4608);       // 4096 bf16
    short* Wvh       = (short*)(ws + 6656);       // 65536 bf16
    short* Bo        = (short*)(ws + 39424);      // 65536 bf16
    // total ws use: ~0.3 MB

    prep_kernel<<<dim3(16), dim3(256), 0, stream>>>(query, Wk, rpe, asw,
                                                    qwk, rpe_exp, rpe_scale);
    pack_kernel<<<dim3(528), dim3(256), 0, stream>>>(qwk, Wv, Wo, Bq, Wvh, Bo);
    fused_kernel<<<dim3(2048), dim3(512), 0, stream>>>(x, rpe_exp, rpe_scale,
                                                       Bq, Wvh, Bo, out);
}